// Round 17
// baseline (132.428 us; speedup 1.0000x reference)
//
#include <hip/hip_runtime.h>
#include <hip/hip_bf16.h>
#include <math.h>

#define BS   32
#define IC   64
#define OC   64
#define HH   128
#define WW   128
#define BANK 256
#define ADDR 64
#define WELEM (OC*IC*9)
#define PLANE (HH*WW)

typedef short short8 __attribute__((ext_vector_type(8)));
typedef float f32x16 __attribute__((ext_vector_type(16)));

__device__ __forceinline__ short f2bf(float f) {
    unsigned u = __builtin_bit_cast(unsigned, f);
    unsigned r = (u + 0x7FFFu + ((u >> 16) & 1u)) >> 16;
    return (short)r;
}

typedef __attribute__((address_space(3))) unsigned int lds_u32;
typedef const __attribute__((address_space(1))) unsigned int g_u32;
__device__ __forceinline__ void gload16(const short* g, short* l) {
    __builtin_amdgcn_global_load_lds((g_u32*)g, (lds_u32*)l, 16, 0, 0);
}

// ---------------- kernel 1: sel_w = softmax(w_addr @ aspace^T) --------------
__global__ __launch_bounds__(BANK) void k_selw(const float* __restrict__ w_addr,
                                               const float* __restrict__ aspace,
                                               float* __restrict__ sel_w) {
    int b = blockIdx.x;
    int n = threadIdx.x;
    const float* wa = w_addr + b * ADDR;
    const float* as = aspace + n * ADDR;
    float dot = 0.f;
#pragma unroll
    for (int k = 0; k < ADDR; ++k) dot = fmaf(wa[k], as[k], dot);

    __shared__ float red[BANK];
    red[n] = dot; __syncthreads();
    for (int s = BANK / 2; s > 0; s >>= 1) {
        if (n < s) red[n] = fmaxf(red[n], red[n + s]);
        __syncthreads();
    }
    float m = red[0]; __syncthreads();
    float e = expf(dot - m);
    red[n] = e; __syncthreads();
    for (int s = BANK / 2; s > 0; s >>= 1) {
        if (n < s) red[n] += red[n + s];
        __syncthreads();
    }
    sel_w[b * BANK + n] = e / red[0];
}

// ---------------- kernel 2: bias[b][o] (R12-proven) -------------------------
__global__ __launch_bounds__(256) void k_bias(const float* __restrict__ b_addr,
                                              const float* __restrict__ aspace,
                                              const float* __restrict__ b_bank,
                                              float* __restrict__ bias) {
    __shared__ float s_m[256], s_s[256], s_w[256];
    int blk = blockIdx.x;            // b*8 + og
    int b   = blk >> 3;
    int og  = blk & 7;
    int tid = threadIdx.x;
    int ol  = tid >> 5;              // 0..7
    int o   = og * 8 + ol;
    int q   = tid & 31;              // n-slice: n = q*8 .. q*8+7

    const float* ba = b_addr + ((size_t)b * OC + o) * ADDR;
    float bav[64];
#pragma unroll
    for (int i = 0; i < 16; ++i)
        *(float4*)&bav[i * 4] = *(const float4*)&ba[i * 4];

    float d[8];
#pragma unroll
    for (int n = 0; n < 8; ++n) {
        const float* ar = aspace + (size_t)(q * 8 + n) * ADDR;
        float s = 0.f;
#pragma unroll
        for (int k = 0; k < 64; ++k) s = fmaf(bav[k], ar[k], s);
        d[n] = s;
    }
    float mx = d[0];
#pragma unroll
    for (int n = 1; n < 8; ++n) mx = fmaxf(mx, d[n]);
    s_m[ol * 32 + q] = mx;
    __syncthreads();
    float M = -1e30f;
    for (int j = 0; j < 32; ++j) M = fmaxf(M, s_m[ol * 32 + j]);

    float s = 0.f, ws = 0.f;
#pragma unroll
    for (int n = 0; n < 8; ++n) {
        float e = expf(d[n] - M);
        s += e;
        ws += e * b_bank[q * 8 + n];
    }
    s_s[ol * 32 + q] = s;
    s_w[ol * 32 + q] = ws;
    __syncthreads();
    if (q == 0) {
        float S = 0.f, W = 0.f;
        for (int j = 0; j < 32; ++j) { S += s_s[ol * 32 + j]; W += s_w[ol * 32 + j]; }
        bias[b * OC + o] = W / S;
    }
}

// ---------------- kernel 3: weight mix -> bf16 (R5-proven split-K) ----------
// wmb[b][tap(9)][icg(8)][oc(64)][ic8(8)]  (bf16)
__global__ __launch_bounds__(256) void k_wmix(const float* __restrict__ sel_w,
                                              const float* __restrict__ w_bank,
                                              __hip_bfloat16* __restrict__ wmb) {
    __shared__ float s_red[4 * 32 * 64];   // [chunk][b][jl] = 32 KB

    int tid = threadIdx.x;
    int jl  = tid & 63;
    int c   = tid >> 6;
    int jb  = blockIdx.x * 64 + jl;

    int n0 = __builtin_amdgcn_readfirstlane(c * 64);
    const float* selp = sel_w + n0;

    float wv[64];
#pragma unroll
    for (int n = 0; n < 64; ++n)
        wv[n] = w_bank[(size_t)(n0 + n) * WELEM + jb];

    float acc[BS];
#pragma unroll
    for (int b = 0; b < BS; ++b) acc[b] = 0.f;
#pragma unroll
    for (int b = 0; b < BS; ++b)
#pragma unroll
        for (int n = 0; n < 64; ++n)
            acc[b] = fmaf(selp[b * BANK + n], wv[n], acc[b]);

#pragma unroll
    for (int b = 0; b < BS; ++b)
        s_red[(c * 32 + b) * 64 + jl] = acc[b];
    __syncthreads();

    int B0  = (tid * 8) & 31;
    int jl2 = (tid * 8) >> 5;
    int j   = blockIdx.x * 64 + jl2;
    int o   = j / 576;
    int rem = j - o * 576;
    int i   = rem / 9;
    int tap = rem - i * 9;
    size_t base = ((size_t)tap * 8 + (i >> 3)) * 512 + (size_t)o * 8 + (i & 7);
#pragma unroll
    for (int u = 0; u < 8; ++u) {
        int b = B0 + u;
        float v = s_red[(0 * 32 + b) * 64 + jl2] + s_red[(1 * 32 + b) * 64 + jl2]
                + s_red[(2 * 32 + b) * 64 + jl2] + s_red[(3 * 32 + b) * 64 + jl2];
        short sv = f2bf(v);
        wmb[(size_t)b * (9 * 8 * 64 * 8) + base] = *reinterpret_cast<__hip_bfloat16*>(&sv);
    }
}

// ---------------- kernel 4: FUSED conv — fat wave tile (64oc x 64px) --------
// 1024 blocks = (b, 32 strips of 4 rows), XCD-swizzled; 512 thr / 8 waves.
// wave = (row wr 0..3, px-half ph): 64 oc x 64 px -> acc[2][2] (64 VGPR).
// LDS reads/MFMA = 1.0 (was 1.5); staged halo 6/4 (was 4/2); MFMA per sync
// event doubled. K: 4 chunks of 16 ic; R16-proven staging structure.
__global__ __launch_bounds__(512, 2) void k_conv(const float* __restrict__ x,
                                                 const short* __restrict__ wmb,
                                                 const float* __restrict__ bias,
                                                 float* __restrict__ out) {
    __shared__ short s_x[2][6 * 2 * 132 * 8];  // [buf][ky6][g][col132][ic8] 25344B x2
    __shared__ short s_w[2][9 * 2 * 64 * 8];   // [buf][tap][g][oc][ic8] 18432B x2
    __shared__ float s_bias[OC];

    int orig    = blockIdx.x;
    int logical = (orig & 7) * 128 + (orig >> 3);   // bijective (1024%8==0)
    int b    = logical >> 5;
    int y0   = (logical & 31) * 4;
    int tid  = threadIdx.x;
    int lane = tid & 63;
    int wv   = tid >> 6;
    int h    = lane >> 5;
    int ln   = lane & 31;
    int wr   = wv & 3;
    int ph   = wv >> 2;

    if (tid < OC) s_bias[tid] = bias[b * OC + tid];
    // halo cols 0 and 129 structurally zero: 12 (ky,g) rows x 2 cols x 2 bufs
    if (tid < 48) {
        int bf  = tid >= 24;
        int r   = tid - bf * 24;
        int kg  = r >> 1;
        int col = (r & 1) ? 129 : 0;
        *(short8*)&s_x[bf][(kg * 132 + col) * 8] = (short8){0,0,0,0,0,0,0,0};
    }

    const float* xb   = x + (size_t)b * IC * PLANE;
    const short* wmbs = wmb + (size_t)b * 36864;

    // ---- x staging descriptors: 1536 units (ky6, g2, cx128), 3/thread ----
    int x_goff[3], x_lds[3]; bool x_ok[3]; int x_g[3];
#pragma unroll
    for (int k = 0; k < 3; ++k) {
        int u  = k * 512 + tid;
        int ky = u >> 8;                  // 0..5
        int g  = (u >> 7) & 1;
        int cx = u & 127;
        int gy = y0 - 1 + ky;
        x_ok[k]   = ((unsigned)gy < (unsigned)HH);
        x_g[k]    = g;
        x_goff[k] = gy * WW + cx;
        x_lds[k]  = ((ky * 2 + g) * 132 + cx + 1) * 8;
    }

    float xr[3][8];

    auto LOADX = [&](int cc) {
#pragma unroll
        for (int k = 0; k < 3; ++k) {
            if (x_ok[k]) {
                const float* p = xb + (size_t)(cc * 16 + x_g[k] * 8) * PLANE + x_goff[k];
#pragma unroll
                for (int e = 0; e < 8; ++e) xr[k][e] = p[(size_t)e * PLANE];
            } else {
#pragma unroll
                for (int e = 0; e < 8; ++e) xr[k][e] = 0.f;
            }
        }
    };
    // w: 18 slices (tap,g); each slice 64 lanes x 16B contiguous, linear dest
    auto STAGEW = [&](int cc, int bf) {
        for (int s = wv; s < 18; s += 8) {
            int tap = s >> 1, g = s & 1;
            const short* gsrc = wmbs + (size_t)((tap * 8 + 2 * cc + g) * 64 + lane) * 8;
            gload16(gsrc, &s_w[bf][((tap * 2 + g) * 64) * 8]);
        }
    };
    auto STOREX = [&](int bf) {
#pragma unroll
        for (int k = 0; k < 3; ++k) {
            short8 s;
#pragma unroll
            for (int e = 0; e < 8; ++e) s[e] = f2bf(xr[k][e]);
            *(short8*)&s_x[bf][x_lds[k]] = s;           // b128, lane-contiguous
        }
    };

    f32x16 acc[2][2];
#pragma unroll
    for (int mt = 0; mt < 2; ++mt)
#pragma unroll
        for (int nt = 0; nt < 2; ++nt) acc[mt][nt] = (f32x16)0.0f;

    LOADX(0);
    STAGEW(0, 0);
    STOREX(0);
    __syncthreads();

#pragma unroll
    for (int cc = 0; cc < 4; ++cc) {
        int bf = cc & 1;
        if (cc < 3) {
            LOADX(cc + 1);                 // x -> regs, in flight during MFMA
            STAGEW(cc + 1, bf ^ 1);        // w -> LDS direct, in flight
            __builtin_amdgcn_sched_barrier(0);   // forbid sinking loads below
        }
        const short8* xb8 = (const short8*)s_x[bf];
        const short8* wb8 = (const short8*)s_w[bf];
#pragma unroll
        for (int ky = 0; ky < 3; ++ky) {
#pragma unroll
            for (int kx = 0; kx < 3; ++kx) {
                short8 a0 = wb8[((ky * 3 + kx) * 2 + h) * 64 + ln];
                short8 a1 = wb8[((ky * 3 + kx) * 2 + h) * 64 + 32 + ln];
#pragma unroll
                for (int nt = 0; nt < 2; ++nt) {
                    short8 bb = xb8[((wr + ky) * 2 + h) * 132 + ph * 64 + nt * 32 + ln + kx];
                    acc[0][nt] = __builtin_amdgcn_mfma_f32_32x32x16_bf16(a0, bb, acc[0][nt], 0, 0, 0);
                    acc[1][nt] = __builtin_amdgcn_mfma_f32_32x32x16_bf16(a1, bb, acc[1][nt], 0, 0, 0);
                }
            }
        }
        if (cc < 3) STOREX(bf ^ 1);        // waits xr; vmcnt drain after MFMA
        __syncthreads();
    }

    // epilogue: C/D layout col=lane&31, row=(r&3)+8*(r>>2)+4*h
    int y = y0 + wr;
    float* ob = out + (size_t)b * OC * PLANE;
#pragma unroll
    for (int mt = 0; mt < 2; ++mt) {
#pragma unroll
        for (int nt = 0; nt < 2; ++nt) {
#pragma unroll
            for (int r = 0; r < 16; ++r) {
                int oc = mt * 32 + (r & 3) + 8 * (r >> 2) + 4 * h;
                int px = ph * 64 + nt * 32 + ln;
                ob[((size_t)oc * HH + y) * WW + px] = acc[mt][nt][r] + s_bias[oc];
            }
        }
    }
}

// ---------------------------------------------------------------------------
extern "C" void kernel_launch(void* const* d_in, const int* in_sizes, int n_in,
                              void* d_out, int out_size, void* d_ws, size_t ws_size,
                              hipStream_t stream) {
    const float* x      = (const float*)d_in[0];
    const float* w_addr = (const float*)d_in[1];
    const float* b_addr = (const float*)d_in[2];
    const float* w_bank = (const float*)d_in[3];
    const float* b_bank = (const float*)d_in[4];
    const float* aspace = (const float*)d_in[5];
    float* out = (float*)d_out;

    char* ws = (char*)d_ws;
    float*          sel_w = (float*)ws;                     // 32768 B
    float*          bias  = (float*)(ws + 32768);           //  8192 B
    __hip_bfloat16* wmb   = (__hip_bfloat16*)(ws + 40960);  // 2359296 B

    k_selw<<<BS, BANK, 0, stream>>>(w_addr, aspace, sel_w);
    k_bias<<<BS * 8, 256, 0, stream>>>(b_addr, aspace, b_bank, bias);
    k_wmix<<<WELEM / 64, 256, 0, stream>>>(sel_w, w_bank, wmb);
    k_conv<<<BS * 32, 512, 0, stream>>>(x, (const short*)wmb, bias, out);
}